// Round 1
// baseline (276.003 us; speedup 1.0000x reference)
//
#include <hip/hip_runtime.h>
#include <stdint.h>

// Problem constants
#define BB 2
#define NN 2048
#define DD 512
#define HH 8
#define DHH 64
// bh count = 16, per-head Q/K/V = 2048*64 elems = 131072

typedef __attribute__((ext_vector_type(8))) short bf16x8;   // 8 bf16 = 4 VGPR
typedef __attribute__((ext_vector_type(4))) float f32x4;    // MFMA C/D frag

static __device__ __forceinline__ unsigned short f2bf(float f) {
    union { float f; unsigned u; } v; v.f = f;
    unsigned r = v.u + 0x7fffu + ((v.u >> 16) & 1u);  // RNE
    return (unsigned short)(r >> 16);
}

// Alias-safe 16B vector load (compiles to global_load_dwordx4 / ds_read_b128)
static __device__ __forceinline__ bf16x8 ld8(const unsigned short* p) {
    bf16x8 v; __builtin_memcpy(&v, p, 16); return v;
}

// ---------------- cast x (fp32 -> bf16), 4 elems/thread ----------------
__global__ void ca_cast_x(const float* __restrict__ x, unsigned short* __restrict__ xb) {
    int gid = blockIdx.x * 256 + threadIdx.x;           // 524288 threads * 4 = 2M
    float4 v = ((const float4*)x)[gid];
    ushort4 o;
    o.x = f2bf(v.x); o.y = f2bf(v.y); o.z = f2bf(v.z); o.w = f2bf(v.w);
    ((ushort4*)xb)[gid] = o;
}

// ------------- cast+transpose weights: WT[n][k] = W[k][n], bf16 -------------
// grid: (64 tiles, 1, 4 matrices), block 256
__global__ void ca_cast_wT(const float* __restrict__ w0, const float* __restrict__ w1,
                           const float* __restrict__ w2, const float* __restrict__ w3,
                           unsigned short* __restrict__ wts) {
    __shared__ float T[64][65];
    int z = blockIdx.z;
    const float* W = (z == 0) ? w0 : (z == 1) ? w1 : (z == 2) ? w2 : w3;
    unsigned short* out = wts + z * 262144;
    int t = blockIdx.x;
    int k0 = (t & 7) << 6, n0 = (t >> 3) << 6;
    int c = threadIdx.x & 63, r4 = threadIdx.x >> 6;
#pragma unroll
    for (int rr = 0; rr < 16; ++rr) {
        int r = r4 * 16 + rr;
        T[r][c] = W[(k0 + r) * 512 + n0 + c];           // coalesced read
    }
    __syncthreads();
#pragma unroll
    for (int rr = 0; rr < 16; ++rr) {
        int r = r4 * 16 + rr;
        out[(n0 + r) * 512 + k0 + c] = f2bf(T[c][r]);   // coalesced write
    }
}

// ------------- QKV projection GEMM (bf16 MFMA, fp32 acc) -------------
// C[4096,512] = xb[4096,512] @ W ; W given transposed WT[512][512].
// Output layout: [bh][N][DH] bf16.  grid (64 m-tiles, 8 n-tiles, 3), block 256 (4 waves)
__global__ void ca_gemm_proj(const unsigned short* __restrict__ A,
                             const unsigned short* __restrict__ wts,
                             unsigned short* __restrict__ qkv) {
    int z = blockIdx.z;
    const unsigned short* BT = wts + z * 262144;
    unsigned short* out = qkv + z * 2097152;
    int w = threadIdx.x >> 6, lane = threadIdx.x & 63;
    int c = lane & 15, qd = lane >> 4;
    int m0 = blockIdx.x * 64 + w * 16;
    int n0 = blockIdx.y * 64;
    f32x4 acc[4];
#pragma unroll
    for (int nb = 0; nb < 4; ++nb) acc[nb] = (f32x4){0.f, 0.f, 0.f, 0.f};
    const unsigned short* Ap = A + (m0 + c) * 512 + qd * 8;
    const unsigned short* Bp = BT + (n0 + c) * 512 + qd * 8;
    for (int k0 = 0; k0 < 512; k0 += 32) {
        bf16x8 a = ld8(Ap + k0);
#pragma unroll
        for (int nb = 0; nb < 4; ++nb) {
            bf16x8 b = ld8(Bp + nb * (16 * 512) + k0);
            acc[nb] = __builtin_amdgcn_mfma_f32_16x16x32_bf16(a, b, acc[nb], 0, 0, 0);
        }
    }
#pragma unroll
    for (int nb = 0; nb < 4; ++nb) {
#pragma unroll
        for (int r = 0; r < 4; ++r) {
            int row = m0 + qd * 4 + r;        // b*2048 + i
            int col = n0 + nb * 16 + c;       // h*64 + d
            int b = row >> 11, i = row & 2047, h = col >> 6, d = col & 63;
            out[(((b << 3) + h) * 2048 + i) * 64 + d] = f2bf(acc[nb][r]);
        }
    }
}

// ------------- V transpose: [bh][N][DH] -> [bh][DH][N] -------------
// grid 512 (bh*32 + itile), block 256
__global__ void ca_transpose_v(const unsigned short* __restrict__ V,
                               unsigned short* __restrict__ VT) {
    __shared__ unsigned short T[64][65];
    int bh = blockIdx.x >> 5, it = blockIdx.x & 31;
    int i0 = it * 64;
    int c = threadIdx.x & 63, r4 = threadIdx.x >> 6;
    const unsigned short* src = V + bh * 131072;
    unsigned short* dst = VT + bh * 131072;
#pragma unroll
    for (int rr = 0; rr < 16; ++rr) {
        int i = r4 * 16 + rr;
        T[i][c] = src[(i0 + i) * 64 + c];
    }
    __syncthreads();
#pragma unroll
    for (int rr = 0; rr < 16; ++rr) {
        int d = r4 * 16 + rr;
        dst[d * 2048 + i0 + c] = T[c][d];
    }
}

// ------------- Flash attention (bf16 MFMA, no online-max: logits bounded) -------------
// grid 512 (bh*32 + itile), block 256 = 4 waves, wave = 16 queries x full head.
__global__ void ca_flash(const unsigned short* __restrict__ Q,
                         const unsigned short* __restrict__ K,
                         const unsigned short* __restrict__ VT,
                         const float* __restrict__ rel_pos,
                         const float* __restrict__ c_emb,
                         unsigned short* __restrict__ Ob) {
    __shared__ float lrel[132], lgate[132];
    __shared__ __align__(16) unsigned short Pt[4][16][32];   // per-wave private slab
    int bh = blockIdx.x >> 5, it = blockIdx.x & 31;
    int b = bh >> 3, h = bh & 7;
    int w = threadIdx.x >> 6, lane = threadIdx.x & 63;
    int c = lane & 15, qd = lane >> 4;
    int i0 = it * 64 + w * 16;
    if (threadIdx.x < 129) {
        lrel[threadIdx.x]  = rel_pos[threadIdx.x * 8 + h];
        lgate[threadIdx.x] = c_emb[threadIdx.x * 8 + h];
    }
    __syncthreads();
    const unsigned short* Qh = Q  + bh * 131072;
    const unsigned short* Kh = K  + bh * 131072;
    const unsigned short* Vh = VT + bh * 131072;

    bf16x8 aq0 = ld8(Qh + (i0 + c) * 64 + qd * 8);
    bf16x8 aq1 = ld8(Qh + (i0 + c) * 64 + 32 + qd * 8);

    f32x4 o[4];
#pragma unroll
    for (int db = 0; db < 4; ++db) o[db] = (f32x4){0.f, 0.f, 0.f, 0.f};
    float lp[4] = {0.f, 0.f, 0.f, 0.f};
    int iq = i0 + qd * 4;

    for (int j0 = 0; j0 < 2048; j0 += 32) {
        f32x4 s0 = (f32x4){0.f, 0.f, 0.f, 0.f};
        f32x4 s1 = (f32x4){0.f, 0.f, 0.f, 0.f};
        {
            bf16x8 bk;
            bk = ld8(Kh + (j0 + c) * 64 + qd * 8);
            s0 = __builtin_amdgcn_mfma_f32_16x16x32_bf16(aq0, bk, s0, 0, 0, 0);
            bk = ld8(Kh + (j0 + c) * 64 + 32 + qd * 8);
            s0 = __builtin_amdgcn_mfma_f32_16x16x32_bf16(aq1, bk, s0, 0, 0, 0);
            bk = ld8(Kh + (j0 + 16 + c) * 64 + qd * 8);
            s1 = __builtin_amdgcn_mfma_f32_16x16x32_bf16(aq0, bk, s1, 0, 0, 0);
            bk = ld8(Kh + (j0 + 16 + c) * 64 + 32 + qd * 8);
            s1 = __builtin_amdgcn_mfma_f32_16x16x32_bf16(aq1, bk, s1, 0, 0, 0);
        }
        // bias + exp + gate; l accumulates ungated exp; P = exp*gate -> LDS (bf16)
#pragma unroll
        for (int r = 0; r < 4; ++r) {
            int i = iq + r;
            int j = j0 + c;
            int d0 = j - i;      d0 = (d0 < -64) ? -64 : (d0 > 64 ? 64 : d0); d0 += 64;
            int d1 = j + 16 - i; d1 = (d1 < -64) ? -64 : (d1 > 64 ? 64 : d1); d1 += 64;
            float t0 = __expf((s0[r] + lrel[d0]) * 0.125f);
            float t1 = __expf((s1[r] + lrel[d1]) * 0.125f);
            lp[r] += t0 + t1;
            Pt[w][qd * 4 + r][c]      = f2bf(t0 * lgate[d0]);
            Pt[w][qd * 4 + r][16 + c] = f2bf(t1 * lgate[d1]);
        }
        // same-wave RAW on Pt: compiler inserts lgkmcnt wait; no barrier needed
        bf16x8 ap = ld8(&Pt[w][c][qd * 8]);   // P A-frag: [m=c][k=qd*8+j]
#pragma unroll
        for (int db = 0; db < 4; ++db) {
            bf16x8 bv = ld8(Vh + (db * 16 + c) * 2048 + j0 + qd * 8);
            o[db] = __builtin_amdgcn_mfma_f32_16x16x32_bf16(ap, bv, o[db], 0, 0, 0);
        }
    }
    // reduce lp across the 16 lanes of each quad (rows live per-quad)
#pragma unroll
    for (int r = 0; r < 4; ++r) {
        lp[r] += __shfl_xor(lp[r], 1);
        lp[r] += __shfl_xor(lp[r], 2);
        lp[r] += __shfl_xor(lp[r], 4);
        lp[r] += __shfl_xor(lp[r], 8);
    }
    // write O as bf16 [4096][512] row-major (row = b*2048+i, col = h*64+dh)
#pragma unroll
    for (int db = 0; db < 4; ++db) {
#pragma unroll
        for (int r = 0; r < 4; ++r) {
            int row = b * 2048 + i0 + qd * 4 + r;
            int col = h * 64 + db * 16 + c;
            Ob[row * 512 + col] = f2bf(o[db][r] / lp[r]);
        }
    }
}

// ------------- Output GEMM: d_out = Ob @ Wo + bo (fp32 out) -------------
// grid (64, 8), block 256
__global__ void ca_gemm_out(const unsigned short* __restrict__ A,
                            const unsigned short* __restrict__ BT,
                            const float* __restrict__ bias,
                            float* __restrict__ out) {
    int w = threadIdx.x >> 6, lane = threadIdx.x & 63;
    int c = lane & 15, qd = lane >> 4;
    int m0 = blockIdx.x * 64 + w * 16;
    int n0 = blockIdx.y * 64;
    f32x4 acc[4];
#pragma unroll
    for (int nb = 0; nb < 4; ++nb) acc[nb] = (f32x4){0.f, 0.f, 0.f, 0.f};
    const unsigned short* Ap = A + (m0 + c) * 512 + qd * 8;
    const unsigned short* Bp = BT + (n0 + c) * 512 + qd * 8;
    for (int k0 = 0; k0 < 512; k0 += 32) {
        bf16x8 a = ld8(Ap + k0);
#pragma unroll
        for (int nb = 0; nb < 4; ++nb) {
            bf16x8 bq = ld8(Bp + nb * (16 * 512) + k0);
            acc[nb] = __builtin_amdgcn_mfma_f32_16x16x32_bf16(a, bq, acc[nb], 0, 0, 0);
        }
    }
#pragma unroll
    for (int nb = 0; nb < 4; ++nb) {
#pragma unroll
        for (int r = 0; r < 4; ++r) {
            int row = m0 + qd * 4 + r;
            int col = n0 + nb * 16 + c;
            out[row * 512 + col] = acc[nb][r] + bias[col];
        }
    }
}

extern "C" void kernel_launch(void* const* d_in, const int* in_sizes, int n_in,
                              void* d_out, int out_size, void* d_ws, size_t ws_size,
                              hipStream_t stream) {
    const float* x   = (const float*)d_in[0];
    const float* Wq  = (const float*)d_in[1];
    const float* Wk  = (const float*)d_in[2];
    const float* Wv  = (const float*)d_in[3];
    const float* rel = (const float*)d_in[4];
    const float* cem = (const float*)d_in[5];
    const float* Wo  = (const float*)d_in[6];
    const float* bo  = (const float*)d_in[7];
    float* out = (float*)d_out;
    char* ws = (char*)d_ws;

    // workspace layout (bytes, all 256-aligned)
    unsigned short* xb  = (unsigned short*)(ws);              // 4 MB  x bf16 [4096][512]
    unsigned short* wts = (unsigned short*)(ws + 4194304);    // 2 MB  WqT,WkT,WvT,WoT bf16 [512][512] each
    unsigned short* qkv = (unsigned short*)(ws + 6291456);    // 12 MB q,k,v bf16 [bh][N][DH] each
    unsigned short* vt  = (unsigned short*)(ws + 18874368);   // 4 MB  vT bf16 [bh][DH][N]
    unsigned short* ob  = (unsigned short*)(ws + 23068672);   // 4 MB  attn out bf16 [4096][512]

    hipLaunchKernelGGL(ca_cast_x, dim3(2048), dim3(256), 0, stream, x, xb);
    hipLaunchKernelGGL(ca_cast_wT, dim3(64, 1, 4), dim3(256), 0, stream, Wq, Wk, Wv, Wo, wts);
    hipLaunchKernelGGL(ca_gemm_proj, dim3(64, 8, 3), dim3(256), 0, stream, xb, wts, qkv);
    hipLaunchKernelGGL(ca_transpose_v, dim3(512), dim3(256), 0, stream, qkv + 2 * 2097152, vt);
    hipLaunchKernelGGL(ca_flash, dim3(512), dim3(256), 0, stream,
                       qkv, qkv + 2097152, vt, rel, cem, ob);
    hipLaunchKernelGGL(ca_gemm_out, dim3(64, 8), dim3(256), 0, stream, ob, wts + 3 * 262144, bo, out);
}

// Round 2
// 219.074 us; speedup vs baseline: 1.2599x; 1.2599x over previous
//
#include <hip/hip_runtime.h>
#include <stdint.h>

// Problem constants
#define BB 2
#define NN 2048
#define DD 512
#define HH 8
#define DHH 64
// bh count = 16, per-head Q/K/V = 2048*64 elems = 131072

typedef __attribute__((ext_vector_type(8))) short bf16x8;   // 8 bf16 = 4 VGPR
typedef __attribute__((ext_vector_type(4))) float f32x4;    // MFMA C/D frag

static __device__ __forceinline__ unsigned short f2bf(float f) {
    union { float f; unsigned u; } v; v.f = f;
    unsigned r = v.u + 0x7fffu + ((v.u >> 16) & 1u);  // RNE
    return (unsigned short)(r >> 16);
}

// pack two positive floats to bf16 pair (round-half-up; inputs are exp() outputs, no NaN/neg)
static __device__ __forceinline__ unsigned pkbf(float a, float b) {
    union { float f; unsigned u; } ua, ub; ua.f = a; ub.f = b;
    return ((ub.u + 0x8000u) & 0xffff0000u) | ((ua.u + 0x8000u) >> 16);
}

// Alias-safe 16B vector load (compiles to global_load_dwordx4 / ds_read_b128)
static __device__ __forceinline__ bf16x8 ld8(const unsigned short* p) {
    bf16x8 v; __builtin_memcpy(&v, p, 16); return v;
}

// ---------------- cast x (fp32 -> bf16), 4 elems/thread ----------------
__global__ void ca_cast_x(const float* __restrict__ x, unsigned short* __restrict__ xb) {
    int gid = blockIdx.x * 256 + threadIdx.x;
    float4 v = ((const float4*)x)[gid];
    ushort4 o;
    o.x = f2bf(v.x); o.y = f2bf(v.y); o.z = f2bf(v.z); o.w = f2bf(v.w);
    ((ushort4*)xb)[gid] = o;
}

// ------------- cast+transpose weights: WT[n][k] = W[k][n], bf16 -------------
__global__ void ca_cast_wT(const float* __restrict__ w0, const float* __restrict__ w1,
                           const float* __restrict__ w2, const float* __restrict__ w3,
                           unsigned short* __restrict__ wts) {
    __shared__ float T[64][65];
    int z = blockIdx.z;
    const float* W = (z == 0) ? w0 : (z == 1) ? w1 : (z == 2) ? w2 : w3;
    unsigned short* out = wts + z * 262144;
    int t = blockIdx.x;
    int k0 = (t & 7) << 6, n0 = (t >> 3) << 6;
    int c = threadIdx.x & 63, r4 = threadIdx.x >> 6;
#pragma unroll
    for (int rr = 0; rr < 16; ++rr) {
        int r = r4 * 16 + rr;
        T[r][c] = W[(k0 + r) * 512 + n0 + c];
    }
    __syncthreads();
#pragma unroll
    for (int rr = 0; rr < 16; ++rr) {
        int r = r4 * 16 + rr;
        out[(n0 + r) * 512 + k0 + c] = f2bf(T[c][r]);
    }
}

// ------------- QKV projection GEMM (bf16 MFMA, fp32 acc) -------------
__global__ void ca_gemm_proj(const unsigned short* __restrict__ A,
                             const unsigned short* __restrict__ wts,
                             unsigned short* __restrict__ qkv) {
    int z = blockIdx.z;
    const unsigned short* BT = wts + z * 262144;
    unsigned short* out = qkv + z * 2097152;
    int w = threadIdx.x >> 6, lane = threadIdx.x & 63;
    int c = lane & 15, qd = lane >> 4;
    int m0 = blockIdx.x * 64 + w * 16;
    int n0 = blockIdx.y * 64;
    f32x4 acc[4];
#pragma unroll
    for (int nb = 0; nb < 4; ++nb) acc[nb] = (f32x4){0.f, 0.f, 0.f, 0.f};
    const unsigned short* Ap = A + (m0 + c) * 512 + qd * 8;
    const unsigned short* Bp = BT + (n0 + c) * 512 + qd * 8;
    for (int k0 = 0; k0 < 512; k0 += 32) {
        bf16x8 a = ld8(Ap + k0);
#pragma unroll
        for (int nb = 0; nb < 4; ++nb) {
            bf16x8 b = ld8(Bp + nb * (16 * 512) + k0);
            acc[nb] = __builtin_amdgcn_mfma_f32_16x16x32_bf16(a, b, acc[nb], 0, 0, 0);
        }
    }
#pragma unroll
    for (int nb = 0; nb < 4; ++nb) {
#pragma unroll
        for (int r = 0; r < 4; ++r) {
            int row = m0 + qd * 4 + r;
            int col = n0 + nb * 16 + c;
            int b = row >> 11, i = row & 2047, h = col >> 6, d = col & 63;
            out[(((b << 3) + h) * 2048 + i) * 64 + d] = f2bf(acc[nb][r]);
        }
    }
}

// ------------- V transpose: [bh][N][DH] -> [bh][DH][N] -------------
__global__ void ca_transpose_v(const unsigned short* __restrict__ V,
                               unsigned short* __restrict__ VT) {
    __shared__ unsigned short T[64][65];
    int bh = blockIdx.x >> 5, it = blockIdx.x & 31;
    int i0 = it * 64;
    int c = threadIdx.x & 63, r4 = threadIdx.x >> 6;
    const unsigned short* src = V + bh * 131072;
    unsigned short* dst = VT + bh * 131072;
#pragma unroll
    for (int rr = 0; rr < 16; ++rr) {
        int i = r4 * 16 + rr;
        T[i][c] = src[(i0 + i) * 64 + c];
    }
    __syncthreads();
#pragma unroll
    for (int rr = 0; rr < 16; ++rr) {
        int d = r4 * 16 + rr;
        dst[d * 2048 + i0 + c] = T[c][d];
    }
}

// ------------- Flash attention v2 -------------
// grid 1024 (bh*64 + itile), block 256 = 4 waves.
// Block = 32 queries (2 q-tiles of 16); wave w handles j-tiles {w, w+4, ..., w+60},
// i.e. a 4-way j-split; partial (o, l) summed across waves at the end (exact: no max rescale).
// K columns interleaved: S-tile col c of s0 <-> j0+2c, of s1 <-> j0+2c+1 (packed u32 P writes).
__global__ __launch_bounds__(256, 4)
void ca_flash(const unsigned short* __restrict__ Q,
              const unsigned short* __restrict__ K,
              const unsigned short* __restrict__ VT,
              const float* __restrict__ rel_pos,
              const float* __restrict__ c_emb,
              unsigned short* __restrict__ Ob) {
    __shared__ float lrel[129], lgate[129];
    __shared__ __align__(16) unsigned Ptu[4][16][16];   // per-wave P slab, u32-packed bf16 pairs
    __shared__ float red[3][64][41];                    // cross-wave (o,l) partials

    int bh = blockIdx.x >> 6, it = blockIdx.x & 63;
    int b = bh >> 3, h = bh & 7;
    int w = threadIdx.x >> 6, lane = threadIdx.x & 63;
    int c = lane & 15, qd = lane >> 4;
    int i0 = it * 32;

    if (threadIdx.x < 129) {
        lrel[threadIdx.x]  = rel_pos[threadIdx.x * 8 + h];
        lgate[threadIdx.x] = c_emb[threadIdx.x * 8 + h];
    }
    __syncthreads();

    const unsigned short* Qh = Q  + bh * 131072;
    const unsigned short* Kh = K  + bh * 131072;
    const unsigned short* Vh = VT + bh * 131072;

    bf16x8 aq[2][2];
#pragma unroll
    for (int qt = 0; qt < 2; ++qt) {
        aq[qt][0] = ld8(Qh + (i0 + qt * 16 + c) * 64 + qd * 8);
        aq[qt][1] = ld8(Qh + (i0 + qt * 16 + c) * 64 + 32 + qd * 8);
    }

    f32x4 o2[2][4];
    float lp2[2][4];
#pragma unroll
    for (int qt = 0; qt < 2; ++qt)
#pragma unroll
        for (int db = 0; db < 4; ++db) {
            o2[qt][db] = (f32x4){0.f, 0.f, 0.f, 0.f};
            lp2[qt][db] = 0.f;
        }

    for (int t = 0; t < 16; ++t) {
        int j0 = (t * 4 + w) * 32;
        // K frags: interleaved column mapping
        bf16x8 bk0a = ld8(Kh + (j0 + 2 * c) * 64 + qd * 8);
        bf16x8 bk0b = ld8(Kh + (j0 + 2 * c) * 64 + 32 + qd * 8);
        bf16x8 bk1a = ld8(Kh + (j0 + 2 * c + 1) * 64 + qd * 8);
        bf16x8 bk1b = ld8(Kh + (j0 + 2 * c + 1) * 64 + 32 + qd * 8);
        // V frags (shared across both q-tiles)
        bf16x8 bv[4];
#pragma unroll
        for (int db = 0; db < 4; ++db)
            bv[db] = ld8(Vh + (db * 16 + c) * 2048 + j0 + qd * 8);

#pragma unroll
        for (int qt = 0; qt < 2; ++qt) {
            f32x4 s0 = (f32x4){0.f, 0.f, 0.f, 0.f};
            f32x4 s1 = (f32x4){0.f, 0.f, 0.f, 0.f};
            s0 = __builtin_amdgcn_mfma_f32_16x16x32_bf16(aq[qt][0], bk0a, s0, 0, 0, 0);
            s0 = __builtin_amdgcn_mfma_f32_16x16x32_bf16(aq[qt][1], bk0b, s0, 0, 0, 0);
            s1 = __builtin_amdgcn_mfma_f32_16x16x32_bf16(aq[qt][0], bk1a, s1, 0, 0, 0);
            s1 = __builtin_amdgcn_mfma_f32_16x16x32_bf16(aq[qt][1], bk1b, s1, 0, 0, 0);

            int iqt0 = i0 + qt * 16;
            int iq = iqt0 + qd * 4;
            bool lowc  = (j0 + 31 - iqt0) <= -64;   // all j-i <= -64
            bool highc = (j0 - (iqt0 + 15)) >= 64;  // all j-i >= 64
            if (lowc || highc) {
                int d = lowc ? 0 : 128;
                float bb = lrel[d];     // wave-uniform -> broadcast
                float g  = lgate[d];
#pragma unroll
                for (int r = 0; r < 4; ++r) {
                    float t0 = __expf((s0[r] + bb) * 0.125f);
                    float t1 = __expf((s1[r] + bb) * 0.125f);
                    lp2[qt][r] += t0 + t1;
                    Ptu[w][qd * 4 + r][c] = pkbf(t0 * g, t1 * g);
                }
            } else {
#pragma unroll
                for (int r = 0; r < 4; ++r) {
                    int i = iq + r;
                    int j = j0 + 2 * c;
                    int d0 = j - i;     d0 = (d0 < -64) ? -64 : (d0 > 64 ? 64 : d0); d0 += 64;
                    int d1 = j + 1 - i; d1 = (d1 < -64) ? -64 : (d1 > 64 ? 64 : d1); d1 += 64;
                    float t0 = __expf((s0[r] + lrel[d0]) * 0.125f);
                    float t1 = __expf((s1[r] + lrel[d1]) * 0.125f);
                    lp2[qt][r] += t0 + t1;
                    Ptu[w][qd * 4 + r][c] = pkbf(t0 * lgate[d0], t1 * lgate[d1]);
                }
            }
            // same-wave RAW on Ptu: lgkmcnt ordering, no barrier needed
            bf16x8 ap = ld8((const unsigned short*)&Ptu[w][c][0] + qd * 8);
#pragma unroll
            for (int db = 0; db < 4; ++db)
                o2[qt][db] = __builtin_amdgcn_mfma_f32_16x16x32_bf16(ap, bv[db], o2[qt][db], 0, 0, 0);
        }
    }

    // cross-wave combine: waves 1-3 dump partials, wave 0 sums + finalizes
    if (w > 0) {
        float* dst = &red[w - 1][lane][0];
#pragma unroll
        for (int qt = 0; qt < 2; ++qt)
#pragma unroll
            for (int db = 0; db < 4; ++db)
#pragma unroll
                for (int r = 0; r < 4; ++r)
                    dst[qt * 16 + db * 4 + r] = o2[qt][db][r];
#pragma unroll
        for (int qt = 0; qt < 2; ++qt)
#pragma unroll
            for (int r = 0; r < 4; ++r)
                dst[32 + qt * 4 + r] = lp2[qt][r];
    }
    __syncthreads();
    if (w == 0) {
#pragma unroll
        for (int ww = 0; ww < 3; ++ww) {
            const float* src = &red[ww][lane][0];
#pragma unroll
            for (int qt = 0; qt < 2; ++qt) {
#pragma unroll
                for (int db = 0; db < 4; ++db)
#pragma unroll
                    for (int r = 0; r < 4; ++r)
                        o2[qt][db][r] += src[qt * 16 + db * 4 + r];
#pragma unroll
                for (int r = 0; r < 4; ++r)
                    lp2[qt][r] += src[32 + qt * 4 + r];
            }
        }
#pragma unroll
        for (int qt = 0; qt < 2; ++qt)
#pragma unroll
            for (int r = 0; r < 4; ++r) {
                lp2[qt][r] += __shfl_xor(lp2[qt][r], 1);
                lp2[qt][r] += __shfl_xor(lp2[qt][r], 2);
                lp2[qt][r] += __shfl_xor(lp2[qt][r], 4);
                lp2[qt][r] += __shfl_xor(lp2[qt][r], 8);
            }
#pragma unroll
        for (int qt = 0; qt < 2; ++qt)
#pragma unroll
            for (int db = 0; db < 4; ++db)
#pragma unroll
                for (int r = 0; r < 4; ++r) {
                    int row = b * 2048 + i0 + qt * 16 + qd * 4 + r;
                    int col = h * 64 + db * 16 + c;
                    Ob[row * 512 + col] = f2bf(o2[qt][db][r] / lp2[qt][r]);
                }
    }
}

// ------------- Output GEMM: d_out = Ob @ Wo + bo (fp32 out) -------------
__global__ void ca_gemm_out(const unsigned short* __restrict__ A,
                            const unsigned short* __restrict__ BT,
                            const float* __restrict__ bias,
                            float* __restrict__ out) {
    int w = threadIdx.x >> 6, lane = threadIdx.x & 63;
    int c = lane & 15, qd = lane >> 4;
    int m0 = blockIdx.x * 64 + w * 16;
    int n0 = blockIdx.y * 64;
    f32x4 acc[4];
#pragma unroll
    for (int nb = 0; nb < 4; ++nb) acc[nb] = (f32x4){0.f, 0.f, 0.f, 0.f};
    const unsigned short* Ap = A + (m0 + c) * 512 + qd * 8;
    const unsigned short* Bp = BT + (n0 + c) * 512 + qd * 8;
    for (int k0 = 0; k0 < 512; k0 += 32) {
        bf16x8 a = ld8(Ap + k0);
#pragma unroll
        for (int nb = 0; nb < 4; ++nb) {
            bf16x8 bq = ld8(Bp + nb * (16 * 512) + k0);
            acc[nb] = __builtin_amdgcn_mfma_f32_16x16x32_bf16(a, bq, acc[nb], 0, 0, 0);
        }
    }
#pragma unroll
    for (int nb = 0; nb < 4; ++nb) {
#pragma unroll
        for (int r = 0; r < 4; ++r) {
            int row = m0 + qd * 4 + r;
            int col = n0 + nb * 16 + c;
            out[row * 512 + col] = acc[nb][r] + bias[col];
        }
    }
}

extern "C" void kernel_launch(void* const* d_in, const int* in_sizes, int n_in,
                              void* d_out, int out_size, void* d_ws, size_t ws_size,
                              hipStream_t stream) {
    const float* x   = (const float*)d_in[0];
    const float* Wq  = (const float*)d_in[1];
    const float* Wk  = (const float*)d_in[2];
    const float* Wv  = (const float*)d_in[3];
    const float* rel = (const float*)d_in[4];
    const float* cem = (const float*)d_in[5];
    const float* Wo  = (const float*)d_in[6];
    const float* bo  = (const float*)d_in[7];
    float* out = (float*)d_out;
    char* ws = (char*)d_ws;

    unsigned short* xb  = (unsigned short*)(ws);              // 4 MB
    unsigned short* wts = (unsigned short*)(ws + 4194304);    // 2 MB
    unsigned short* qkv = (unsigned short*)(ws + 6291456);    // 12 MB
    unsigned short* vt  = (unsigned short*)(ws + 18874368);   // 4 MB
    unsigned short* ob  = (unsigned short*)(ws + 23068672);   // 4 MB

    hipLaunchKernelGGL(ca_cast_x, dim3(2048), dim3(256), 0, stream, x, xb);
    hipLaunchKernelGGL(ca_cast_wT, dim3(64, 1, 4), dim3(256), 0, stream, Wq, Wk, Wv, Wo, wts);
    hipLaunchKernelGGL(ca_gemm_proj, dim3(64, 8, 3), dim3(256), 0, stream, xb, wts, qkv);
    hipLaunchKernelGGL(ca_transpose_v, dim3(512), dim3(256), 0, stream, qkv + 2 * 2097152, vt);
    hipLaunchKernelGGL(ca_flash, dim3(1024), dim3(256), 0, stream,
                       qkv, qkv + 2097152, vt, rel, cem, ob);
    hipLaunchKernelGGL(ca_gemm_out, dim3(64, 8), dim3(256), 0, stream, ob, wts + 3 * 262144, bo, out);
}